// Round 1
// baseline (611.375 us; speedup 1.0000x reference)
//
#include <hip/hip_runtime.h>
#include <math.h>

#define N_PTS 8192
#define KFULL 40
#define KNB 20

__device__ __forceinline__ unsigned long long umin64(unsigned long long a, unsigned long long b) {
  return a < b ? a : b;
}

// ---------------------------------------------------------------------------
// kNN: one block per query point. 8192 candidate keys (sortable dist | idx)
// held in registers (32 per thread), 40 iterations of block-wide argmin.
// ---------------------------------------------------------------------------
__global__ __launch_bounds__(256) void knn_kernel(const float* __restrict__ pos,
                                                  int* __restrict__ idx_out) {
  const int i = blockIdx.x;
  const int t = threadIdx.x;
  const float qx = pos[i * 3 + 0], qy = pos[i * 3 + 1], qz = pos[i * 3 + 2];
  const float qs = qx * qx + qy * qy + qz * qz;

  unsigned long long key[32];
#pragma unroll
  for (int s = 0; s < 32; ++s) {
    const int j = t + (s << 8);
    const float x = pos[j * 3 + 0], y = pos[j * 3 + 1], z = pos[j * 3 + 2];
    const float sj = x * x + y * y + z * z;
    const float dt = qx * x + qy * y + qz * z;
    const float d = qs + sj - 2.0f * dt;
    unsigned int b = __float_as_uint(d);
    b = (b & 0x80000000u) ? ~b : (b | 0x80000000u);  // order-preserving map
    unsigned long long k = ((unsigned long long)b << 13) | (unsigned long long)j;
    if (j == i) k = ~0ull;  // exclude self
    key[s] = k;
  }

  __shared__ unsigned long long red[4];
  for (int sel = 0; sel < KFULL; ++sel) {
    unsigned long long m = key[0];
#pragma unroll
    for (int s = 1; s < 32; ++s) m = umin64(m, key[s]);
#pragma unroll
    for (int off = 32; off > 0; off >>= 1)
      m = umin64(m, (unsigned long long)__shfl_xor((unsigned long long)m, off));
    if ((t & 63) == 0) red[t >> 6] = m;
    __syncthreads();
    const unsigned long long w =
        umin64(umin64(red[0], red[1]), umin64(red[2], red[3]));
    const int j = (int)(w & 0x1FFFull);
    if (t == (j & 255)) {
      idx_out[i * KFULL + sel] = j;
      const int s = j >> 8;
#pragma unroll
      for (int ss = 0; ss < 32; ++ss)
        if (ss == s) key[ss] = ~0ull;  // static indices only (no scratch)
    }
    __syncthreads();
  }
}

// ---------------------------------------------------------------------------
// Lift: A0 = pos @ W0[0:3] + b0 ; P0 = pos @ W0[3:6]  -> AP0 [N, 256]
// ---------------------------------------------------------------------------
__global__ __launch_bounds__(128) void lift_kernel(const float* __restrict__ pos,
                                                   const float* __restrict__ W0,
                                                   const float* __restrict__ b0,
                                                   float* __restrict__ AP0) {
  const int i = blockIdx.x;
  const int c = threadIdx.x;
  const float px = pos[i * 3 + 0], py = pos[i * 3 + 1], pz = pos[i * 3 + 2];
  const float a = b0[c] + px * W0[c] + py * W0[128 + c] + pz * W0[256 + c];
  const float p = px * W0[384 + c] + py * W0[512 + c] + pz * W0[640 + c];
  AP0[(size_t)i * 256 + c] = a;
  AP0[(size_t)i * 256 + 128 + c] = p;
}

// ---------------------------------------------------------------------------
// Generic fp32 GEMM: out[m,n] = act( H[m,:] @ W[:,n] + bias[n] )
// K = 128 fixed. W given as two row-major panels Wt (n < NA) / Wb (n >= NA),
// both with row stride ldw. BM=BN=64, BK=32, 256 threads, 4x4 per thread.
// ---------------------------------------------------------------------------
__global__ __launch_bounds__(256) void gemm_kernel(
    const float* __restrict__ H, const float* __restrict__ Wt,
    const float* __restrict__ Wb, int ldw, int NA, int Ntot,
    const float* __restrict__ bias, float slope, int use_act,
    float* __restrict__ out) {
  __shared__ float Hst[32][64];  // [kk][row] (transposed for float4 reads)
  __shared__ float Ws[32][64];   // [kk][n]
  const int bm = blockIdx.x * 64;
  const int bn = blockIdx.y * 64;
  const float* Wbase;
  const float* bptr = nullptr;
  if (bn < NA) {
    Wbase = Wt + bn;
    bptr = bias + bn;
  } else {
    Wbase = Wb + (bn - NA);
  }
  const int tid = threadIdx.x;
  const int tx = tid & 15, ty = tid >> 4;
  float acc[4][4] = {{0.f, 0.f, 0.f, 0.f},
                     {0.f, 0.f, 0.f, 0.f},
                     {0.f, 0.f, 0.f, 0.f},
                     {0.f, 0.f, 0.f, 0.f}};

  for (int k0 = 0; k0 < 128; k0 += 32) {
    __syncthreads();
    {
      const int r = tid >> 3;          // 0..31
      const int kq = (tid & 7) << 2;   // 0,4,..,28
      const float4 v0 = *(const float4*)(H + (size_t)(bm + r) * 128 + k0 + kq);
      const float4 v1 = *(const float4*)(H + (size_t)(bm + r + 32) * 128 + k0 + kq);
      Hst[kq + 0][r] = v0.x; Hst[kq + 1][r] = v0.y;
      Hst[kq + 2][r] = v0.z; Hst[kq + 3][r] = v0.w;
      Hst[kq + 0][r + 32] = v1.x; Hst[kq + 1][r + 32] = v1.y;
      Hst[kq + 2][r + 32] = v1.z; Hst[kq + 3][r + 32] = v1.w;

      const int kw = tid >> 4;         // 0..15
      const int nq = (tid & 15) << 2;  // 0,4,..,60
      const float4 w0 = *(const float4*)(Wbase + (size_t)(k0 + kw) * ldw + nq);
      const float4 w1 = *(const float4*)(Wbase + (size_t)(k0 + kw + 16) * ldw + nq);
      *(float4*)&Ws[kw][nq] = w0;
      *(float4*)&Ws[kw + 16][nq] = w1;
    }
    __syncthreads();
#pragma unroll
    for (int kk = 0; kk < 32; ++kk) {
      const float4 a = *(const float4*)&Hst[kk][ty << 2];
      const float4 b = *(const float4*)&Ws[kk][tx << 2];
      acc[0][0] = fmaf(a.x, b.x, acc[0][0]);
      acc[0][1] = fmaf(a.x, b.y, acc[0][1]);
      acc[0][2] = fmaf(a.x, b.z, acc[0][2]);
      acc[0][3] = fmaf(a.x, b.w, acc[0][3]);
      acc[1][0] = fmaf(a.y, b.x, acc[1][0]);
      acc[1][1] = fmaf(a.y, b.y, acc[1][1]);
      acc[1][2] = fmaf(a.y, b.z, acc[1][2]);
      acc[1][3] = fmaf(a.y, b.w, acc[1][3]);
      acc[2][0] = fmaf(a.z, b.x, acc[2][0]);
      acc[2][1] = fmaf(a.z, b.y, acc[2][1]);
      acc[2][2] = fmaf(a.z, b.z, acc[2][2]);
      acc[2][3] = fmaf(a.z, b.w, acc[2][3]);
      acc[3][0] = fmaf(a.w, b.x, acc[3][0]);
      acc[3][1] = fmaf(a.w, b.y, acc[3][1]);
      acc[3][2] = fmaf(a.w, b.z, acc[3][2]);
      acc[3][3] = fmaf(a.w, b.w, acc[3][3]);
    }
  }

#pragma unroll
  for (int mr = 0; mr < 4; ++mr) {
    const int row = bm + (ty << 2) + mr;
    float r0 = acc[mr][0], r1 = acc[mr][1], r2 = acc[mr][2], r3 = acc[mr][3];
    const int n = tx << 2;
    if (bptr) {
      r0 += bptr[n + 0]; r1 += bptr[n + 1]; r2 += bptr[n + 2]; r3 += bptr[n + 3];
    }
    if (use_act) {
      r0 = r0 > 0.f ? r0 : r0 * slope;
      r1 = r1 > 0.f ? r1 : r1 * slope;
      r2 = r2 > 0.f ? r2 : r2 * slope;
      r3 = r3 > 0.f ? r3 : r3 * slope;
    }
    float4 st = {r0, r1, r2, r3};
    *(float4*)(out + (size_t)row * Ntot + bn + n) = st;
  }
}

// ---------------------------------------------------------------------------
// Gather-max + combine: out[i,c] = LR(A[i,c] - P[i,c] + max_j P[nbr_j, c], 0.2)
// AP layout: [N, Ntot], A = cols [0,NA), P = cols [NA, 2NA).
// ---------------------------------------------------------------------------
__global__ __launch_bounds__(128) void gather_max_kernel(
    const float* __restrict__ AP, const int* __restrict__ idx, int Ntot, int NA,
    int dil, float* __restrict__ out) {
  const int i = blockIdx.x;
  const int c = blockIdx.y * 128 + threadIdx.x;
  const float* P = AP + NA;
  float m = -INFINITY;
#pragma unroll
  for (int j = 0; j < KNB; ++j) {
    const int n = idx[i * KFULL + j * dil];
    m = fmaxf(m, P[(size_t)n * Ntot + c]);
  }
  const float a = AP[(size_t)i * Ntot + c];
  const float p = P[(size_t)i * Ntot + c];
  float v = a - p + m;
  v = v > 0.f ? v : 0.2f * v;
  out[(size_t)i * NA + c] = v;
}

// residual: h += 0.5*(B1+B2)
__global__ __launch_bounds__(256) void combine_kernel(float* __restrict__ h,
                                                      const float* __restrict__ B1,
                                                      const float* __restrict__ B2) {
  const int i = blockIdx.x * 256 + threadIdx.x;
  h[i] += 0.5f * (B1[i] + B2[i]);
}

// ---------------------------------------------------------------------------
// Final projection: q = T @ Wr2 + br2   (T: [32768,128], Wr2: [128,3])
// ---------------------------------------------------------------------------
__global__ __launch_bounds__(128) void recon2_kernel(const float* __restrict__ T,
                                                     const float* __restrict__ Wr2,
                                                     const float* __restrict__ br2,
                                                     float* __restrict__ out) {
  __shared__ float tile[32][129];
  __shared__ float w2[384];
  const int tid = threadIdx.x;
  const int r0 = blockIdx.x * 32;
  w2[tid] = Wr2[tid];
  w2[tid + 128] = Wr2[tid + 128];
  w2[tid + 256] = Wr2[tid + 256];
  for (int s = 0; s < 32; ++s) tile[s][tid] = T[(size_t)(r0 + s) * 128 + tid];
  __syncthreads();
  if (tid < 96) {
    const int r = tid / 3, n = tid % 3;
    float acc = br2[n];
#pragma unroll
    for (int k = 0; k < 128; ++k) acc = fmaf(tile[r][k], w2[k * 3 + n], acc);
    out[(size_t)(r0 + r) * 3 + n] = acc;
  }
}

// ---------------------------------------------------------------------------
extern "C" void kernel_launch(void* const* d_in, const int* in_sizes, int n_in,
                              void* d_out, int out_size, void* d_ws, size_t ws_size,
                              hipStream_t stream) {
  const float* x = (const float*)d_in[0];
  const float* W0 = (const float*)d_in[1];
  const float* b0 = (const float*)d_in[2];
  const float* Wg = (const float*)d_in[3];
  const float* bg = (const float*)d_in[4];
  const float* Wu = (const float*)d_in[5];
  const float* bu = (const float*)d_in[6];
  const float* Wr1 = (const float*)d_in[7];
  const float* br1 = (const float*)d_in[8];
  const float* Wr2 = (const float*)d_in[9];
  const float* br2 = (const float*)d_in[10];
  float* out = (float*)d_out;

  // workspace layout (bytes):
  //   idx 1,310,720 | h 4 MB | AP 32 MB (T aliases) | B1 4 MB | B2 4 MB | U 16 MB
  char* w = (char*)d_ws;
  int* idx = (int*)(w);
  float* h = (float*)(w + 1310720);
  float* AP = (float*)(w + 5505024);
  float* B1 = (float*)(w + 39059456);
  float* B2 = (float*)(w + 43253760);
  float* U = (float*)(w + 47448064);
  float* T = AP;  // AP dead by the time T is produced

  knn_kernel<<<N_PTS, 256, 0, stream>>>(x, idx);

  // lift 3 -> 128 via factorized EdgeConv
  lift_kernel<<<N_PTS, 128, 0, stream>>>(x, W0, b0, AP);
  gather_max_kernel<<<dim3(N_PTS, 1), 128, 0, stream>>>(AP, idx, 256, 128, 1, h);

  // 2 inception blocks x 2 dilated branches
  for (int li = 0; li < 4; ++li) {
    const float* Wt = Wg + (size_t)li * 256 * 128;
    const float* Wb = Wt + 128 * 128;
    const float* bgi = bg + li * 128;
    gemm_kernel<<<dim3(128, 4), 256, 0, stream>>>(h, Wt, Wb, 128, 128, 256, bgi,
                                                  0.f, 0, AP);
    const int dil = (li & 1) ? 2 : 1;
    float* Bd = (li & 1) ? B2 : B1;
    gather_max_kernel<<<dim3(N_PTS, 1), 128, 0, stream>>>(AP, idx, 256, 128, dil, Bd);
    if (li & 1) combine_kernel<<<4096, 256, 0, stream>>>(h, B1, B2);
  }

  // NodeShuffle upsampler: EdgeConv to r*C=512, reshape is free (row-major)
  gemm_kernel<<<dim3(128, 16), 256, 0, stream>>>(h, Wu, Wu + 128 * 512, 512, 512,
                                                 1024, bu, 0.f, 0, AP);
  gather_max_kernel<<<dim3(N_PTS, 4), 128, 0, stream>>>(AP, idx, 1024, 512, 1, U);

  // reconstructor MLP
  gemm_kernel<<<dim3(512, 2), 256, 0, stream>>>(U, Wr1, Wr1, 128, 128, 128, br1,
                                                0.01f, 1, T);
  recon2_kernel<<<1024, 128, 0, stream>>>(T, Wr2, br2, out);
}

// Round 2
// 311.795 us; speedup vs baseline: 1.9608x; 1.9608x over previous
//
#include <hip/hip_runtime.h>
#include <math.h>

#define N_PTS 8192
#define KFULL 40
#define KNB 20

#define NBUCK 4096
#define CAP 2048

// ---------------------------------------------------------------------------
// kNN via histogram select: one block of 256 threads per query point.
// Pass 1: 12-bit histogram of the order-preserving float map (LDS atomics).
// Scan:   find cutoff bucket B* containing the 40th-smallest key.
// Pass 2: recompute maps, compact keys with bucket <= B* into LDS.
// Sort:   broadcast rank-sort of the ~40-80 candidates, write 40 sorted idx.
// Key = (map << 13) | j  reproduces top_k's dist-then-index tie-break.
// ---------------------------------------------------------------------------
__global__ __launch_bounds__(256) void knn_kernel(const float* __restrict__ pos,
                                                  int* __restrict__ idx_out) {
  __shared__ unsigned int smem[NBUCK];  // 16 KB: hist, then reused as cand
  __shared__ unsigned int wave_tot[4];
  __shared__ int s_bstar;
  __shared__ int s_cnt;
  unsigned long long* cand = (unsigned long long*)smem;

  const int i = blockIdx.x;
  const int t = threadIdx.x;
  const float qx = pos[i * 3 + 0], qy = pos[i * 3 + 1], qz = pos[i * 3 + 2];
  const float qs = qx * qx + qy * qy + qz * qz;

  for (int b = t; b < NBUCK; b += 256) smem[b] = 0;
  if (t == 0) s_cnt = 0;
  __syncthreads();

  // ---- pass 1: histogram ----
#pragma unroll
  for (int s = 0; s < 32; ++s) {
    const int j = t + (s << 8);
    const float x = pos[j * 3 + 0], y = pos[j * 3 + 1], z = pos[j * 3 + 2];
    const float sj = x * x + y * y + z * z;
    const float dt = qx * x + qy * y + qz * z;
    const float d = qs + sj - 2.0f * dt;
    unsigned int b = __float_as_uint(d);
    b = (b & 0x80000000u) ? ~b : (b | 0x80000000u);
    if (j != i) atomicAdd(&smem[b >> 20], 1u);
  }
  __syncthreads();

  // ---- scan: find cutoff bucket ----
  const int b0 = t * (NBUCK / 256);
  unsigned int lsum = 0;
#pragma unroll
  for (int b = 0; b < NBUCK / 256; ++b) lsum += smem[b0 + b];
  unsigned int inc = lsum;
#pragma unroll
  for (int off = 1; off < 64; off <<= 1) {
    const unsigned int u = __shfl_up(inc, off);
    if ((t & 63) >= off) inc += u;
  }
  if ((t & 63) == 63) wave_tot[t >> 6] = inc;
  __syncthreads();
  unsigned int wpre = 0;
  for (int wv = 0; wv < (t >> 6); ++wv) wpre += wave_tot[wv];
  const unsigned int excl = wpre + inc - lsum;
  if (excl < (unsigned)KFULL && excl + lsum >= (unsigned)KFULL) {
    unsigned int cum = excl;
    int b = 0;
    for (; b < NBUCK / 256; ++b) {
      cum += smem[b0 + b];
      if (cum >= (unsigned)KFULL) break;
    }
    s_bstar = b0 + b;
  }
  __syncthreads();
  const unsigned int bstar = (unsigned int)s_bstar;
  __syncthreads();  // everyone has bstar; smem may now be reused as cand

  // ---- pass 2: compact candidates ----
#pragma unroll
  for (int s = 0; s < 32; ++s) {
    const int j = t + (s << 8);
    const float x = pos[j * 3 + 0], y = pos[j * 3 + 1], z = pos[j * 3 + 2];
    const float sj = x * x + y * y + z * z;
    const float dt = qx * x + qy * y + qz * z;
    const float d = qs + sj - 2.0f * dt;
    unsigned int b = __float_as_uint(d);
    b = (b & 0x80000000u) ? ~b : (b | 0x80000000u);
    if (j != i && (b >> 20) <= bstar) {
      const int slot = atomicAdd(&s_cnt, 1);
      if (slot < CAP)
        cand[slot] = ((unsigned long long)b << 13) | (unsigned long long)j;
    }
  }
  __syncthreads();

  // ---- rank sort (candidates small; cand[c] reads are lane-broadcast) ----
  const int cnt = s_cnt < CAP ? s_cnt : CAP;
  for (int c0 = t; c0 < cnt; c0 += 256) {
    const unsigned long long my = cand[c0];
    int rank = 0;
    for (int c = 0; c < cnt; ++c) rank += (cand[c] < my) ? 1 : 0;
    if (rank < KFULL) idx_out[i * KFULL + rank] = (int)(my & 0x1FFFull);
  }
}

// ---------------------------------------------------------------------------
// Lift: A0 = pos @ W0[0:3] + b0 ; P0 = pos @ W0[3:6]  -> AP0 [N, 256]
// ---------------------------------------------------------------------------
__global__ __launch_bounds__(128) void lift_kernel(const float* __restrict__ pos,
                                                   const float* __restrict__ W0,
                                                   const float* __restrict__ b0,
                                                   float* __restrict__ AP0) {
  const int i = blockIdx.x;
  const int c = threadIdx.x;
  const float px = pos[i * 3 + 0], py = pos[i * 3 + 1], pz = pos[i * 3 + 2];
  const float a = b0[c] + px * W0[c] + py * W0[128 + c] + pz * W0[256 + c];
  const float p = px * W0[384 + c] + py * W0[512 + c] + pz * W0[640 + c];
  AP0[(size_t)i * 256 + c] = a;
  AP0[(size_t)i * 256 + 128 + c] = p;
}

// ---------------------------------------------------------------------------
// Generic fp32 GEMM: out[m,n] = act( H[m,:] @ W[:,n] + bias[n] )
// K = 128 fixed. W given as two row-major panels Wt (n < NA) / Wb (n >= NA),
// both with row stride ldw. BM=BN=64, BK=32, 256 threads, 4x4 per thread.
// ---------------------------------------------------------------------------
__global__ __launch_bounds__(256) void gemm_kernel(
    const float* __restrict__ H, const float* __restrict__ Wt,
    const float* __restrict__ Wb, int ldw, int NA, int Ntot,
    const float* __restrict__ bias, float slope, int use_act,
    float* __restrict__ out) {
  __shared__ float Hst[32][64];  // [kk][row] (transposed for float4 reads)
  __shared__ float Ws[32][64];   // [kk][n]
  const int bm = blockIdx.x * 64;
  const int bn = blockIdx.y * 64;
  const float* Wbase;
  const float* bptr = nullptr;
  if (bn < NA) {
    Wbase = Wt + bn;
    bptr = bias + bn;
  } else {
    Wbase = Wb + (bn - NA);
  }
  const int tid = threadIdx.x;
  const int tx = tid & 15, ty = tid >> 4;
  float acc[4][4] = {{0.f, 0.f, 0.f, 0.f},
                     {0.f, 0.f, 0.f, 0.f},
                     {0.f, 0.f, 0.f, 0.f},
                     {0.f, 0.f, 0.f, 0.f}};

  for (int k0 = 0; k0 < 128; k0 += 32) {
    __syncthreads();
    {
      const int r = tid >> 3;          // 0..31
      const int kq = (tid & 7) << 2;   // 0,4,..,28
      const float4 v0 = *(const float4*)(H + (size_t)(bm + r) * 128 + k0 + kq);
      const float4 v1 = *(const float4*)(H + (size_t)(bm + r + 32) * 128 + k0 + kq);
      Hst[kq + 0][r] = v0.x; Hst[kq + 1][r] = v0.y;
      Hst[kq + 2][r] = v0.z; Hst[kq + 3][r] = v0.w;
      Hst[kq + 0][r + 32] = v1.x; Hst[kq + 1][r + 32] = v1.y;
      Hst[kq + 2][r + 32] = v1.z; Hst[kq + 3][r + 32] = v1.w;

      const int kw = tid >> 4;         // 0..15
      const int nq = (tid & 15) << 2;  // 0,4,..,60
      const float4 w0 = *(const float4*)(Wbase + (size_t)(k0 + kw) * ldw + nq);
      const float4 w1 = *(const float4*)(Wbase + (size_t)(k0 + kw + 16) * ldw + nq);
      *(float4*)&Ws[kw][nq] = w0;
      *(float4*)&Ws[kw + 16][nq] = w1;
    }
    __syncthreads();
#pragma unroll
    for (int kk = 0; kk < 32; ++kk) {
      const float4 a = *(const float4*)&Hst[kk][ty << 2];
      const float4 b = *(const float4*)&Ws[kk][tx << 2];
      acc[0][0] = fmaf(a.x, b.x, acc[0][0]);
      acc[0][1] = fmaf(a.x, b.y, acc[0][1]);
      acc[0][2] = fmaf(a.x, b.z, acc[0][2]);
      acc[0][3] = fmaf(a.x, b.w, acc[0][3]);
      acc[1][0] = fmaf(a.y, b.x, acc[1][0]);
      acc[1][1] = fmaf(a.y, b.y, acc[1][1]);
      acc[1][2] = fmaf(a.y, b.z, acc[1][2]);
      acc[1][3] = fmaf(a.y, b.w, acc[1][3]);
      acc[2][0] = fmaf(a.z, b.x, acc[2][0]);
      acc[2][1] = fmaf(a.z, b.y, acc[2][1]);
      acc[2][2] = fmaf(a.z, b.z, acc[2][2]);
      acc[2][3] = fmaf(a.z, b.w, acc[2][3]);
      acc[3][0] = fmaf(a.w, b.x, acc[3][0]);
      acc[3][1] = fmaf(a.w, b.y, acc[3][1]);
      acc[3][2] = fmaf(a.w, b.z, acc[3][2]);
      acc[3][3] = fmaf(a.w, b.w, acc[3][3]);
    }
  }

#pragma unroll
  for (int mr = 0; mr < 4; ++mr) {
    const int row = bm + (ty << 2) + mr;
    float r0 = acc[mr][0], r1 = acc[mr][1], r2 = acc[mr][2], r3 = acc[mr][3];
    const int n = tx << 2;
    if (bptr) {
      r0 += bptr[n + 0]; r1 += bptr[n + 1]; r2 += bptr[n + 2]; r3 += bptr[n + 3];
    }
    if (use_act) {
      r0 = r0 > 0.f ? r0 : r0 * slope;
      r1 = r1 > 0.f ? r1 : r1 * slope;
      r2 = r2 > 0.f ? r2 : r2 * slope;
      r3 = r3 > 0.f ? r3 : r3 * slope;
    }
    float4 st = {r0, r1, r2, r3};
    *(float4*)(out + (size_t)row * Ntot + bn + n) = st;
  }
}

// ---------------------------------------------------------------------------
// Gather-max + combine: out[i,c] = LR(A[i,c] - P[i,c] + max_j P[nbr_j, c], 0.2)
// AP layout: [N, Ntot], A = cols [0,NA), P = cols [NA, 2NA).
// ---------------------------------------------------------------------------
__global__ __launch_bounds__(128) void gather_max_kernel(
    const float* __restrict__ AP, const int* __restrict__ idx, int Ntot, int NA,
    int dil, float* __restrict__ out) {
  const int i = blockIdx.x;
  const int c = blockIdx.y * 128 + threadIdx.x;
  const float* P = AP + NA;
  float m = -INFINITY;
#pragma unroll
  for (int j = 0; j < KNB; ++j) {
    const int n = idx[i * KFULL + j * dil];
    m = fmaxf(m, P[(size_t)n * Ntot + c]);
  }
  const float a = AP[(size_t)i * Ntot + c];
  const float p = P[(size_t)i * Ntot + c];
  float v = a - p + m;
  v = v > 0.f ? v : 0.2f * v;
  out[(size_t)i * NA + c] = v;
}

// residual: h += 0.5*(B1+B2)
__global__ __launch_bounds__(256) void combine_kernel(float* __restrict__ h,
                                                      const float* __restrict__ B1,
                                                      const float* __restrict__ B2) {
  const int i = blockIdx.x * 256 + threadIdx.x;
  h[i] += 0.5f * (B1[i] + B2[i]);
}

// ---------------------------------------------------------------------------
// Final projection: q = T @ Wr2 + br2   (T: [32768,128], Wr2: [128,3])
// ---------------------------------------------------------------------------
__global__ __launch_bounds__(128) void recon2_kernel(const float* __restrict__ T,
                                                     const float* __restrict__ Wr2,
                                                     const float* __restrict__ br2,
                                                     float* __restrict__ out) {
  __shared__ float tile[32][129];
  __shared__ float w2[384];
  const int tid = threadIdx.x;
  const int r0 = blockIdx.x * 32;
  w2[tid] = Wr2[tid];
  w2[tid + 128] = Wr2[tid + 128];
  w2[tid + 256] = Wr2[tid + 256];
  for (int s = 0; s < 32; ++s) tile[s][tid] = T[(size_t)(r0 + s) * 128 + tid];
  __syncthreads();
  if (tid < 96) {
    const int r = tid / 3, n = tid % 3;
    float acc = br2[n];
#pragma unroll
    for (int k = 0; k < 128; ++k) acc = fmaf(tile[r][k], w2[k * 3 + n], acc);
    out[(size_t)(r0 + r) * 3 + n] = acc;
  }
}

// ---------------------------------------------------------------------------
extern "C" void kernel_launch(void* const* d_in, const int* in_sizes, int n_in,
                              void* d_out, int out_size, void* d_ws, size_t ws_size,
                              hipStream_t stream) {
  const float* x = (const float*)d_in[0];
  const float* W0 = (const float*)d_in[1];
  const float* b0 = (const float*)d_in[2];
  const float* Wg = (const float*)d_in[3];
  const float* bg = (const float*)d_in[4];
  const float* Wu = (const float*)d_in[5];
  const float* bu = (const float*)d_in[6];
  const float* Wr1 = (const float*)d_in[7];
  const float* br1 = (const float*)d_in[8];
  const float* Wr2 = (const float*)d_in[9];
  const float* br2 = (const float*)d_in[10];
  float* out = (float*)d_out;

  // workspace layout (bytes):
  //   idx 1,310,720 | h 4 MB | AP 32 MB (T aliases) | B1 4 MB | B2 4 MB | U 16 MB
  char* w = (char*)d_ws;
  int* idx = (int*)(w);
  float* h = (float*)(w + 1310720);
  float* AP = (float*)(w + 5505024);
  float* B1 = (float*)(w + 39059456);
  float* B2 = (float*)(w + 43253760);
  float* U = (float*)(w + 47448064);
  float* T = AP;  // AP dead by the time T is produced

  knn_kernel<<<N_PTS, 256, 0, stream>>>(x, idx);

  // lift 3 -> 128 via factorized EdgeConv
  lift_kernel<<<N_PTS, 128, 0, stream>>>(x, W0, b0, AP);
  gather_max_kernel<<<dim3(N_PTS, 1), 128, 0, stream>>>(AP, idx, 256, 128, 1, h);

  // 2 inception blocks x 2 dilated branches
  for (int li = 0; li < 4; ++li) {
    const float* Wt = Wg + (size_t)li * 256 * 128;
    const float* Wb = Wt + 128 * 128;
    const float* bgi = bg + li * 128;
    gemm_kernel<<<dim3(128, 4), 256, 0, stream>>>(h, Wt, Wb, 128, 128, 256, bgi,
                                                  0.f, 0, AP);
    const int dil = (li & 1) ? 2 : 1;
    float* Bd = (li & 1) ? B2 : B1;
    gather_max_kernel<<<dim3(N_PTS, 1), 128, 0, stream>>>(AP, idx, 256, 128, dil, Bd);
    if (li & 1) combine_kernel<<<4096, 256, 0, stream>>>(h, B1, B2);
  }

  // NodeShuffle upsampler: EdgeConv to r*C=512, reshape is free (row-major)
  gemm_kernel<<<dim3(128, 16), 256, 0, stream>>>(h, Wu, Wu + 128 * 512, 512, 512,
                                                 1024, bu, 0.f, 0, AP);
  gather_max_kernel<<<dim3(N_PTS, 4), 128, 0, stream>>>(AP, idx, 1024, 512, 1, U);

  // reconstructor MLP
  gemm_kernel<<<dim3(512, 2), 256, 0, stream>>>(U, Wr1, Wr1, 128, 128, 128, br1,
                                                0.01f, 1, T);
  recon2_kernel<<<1024, 128, 0, stream>>>(T, Wr2, br2, out);
}

// Round 3
// 249.462 us; speedup vs baseline: 2.4508x; 1.2499x over previous
//
#include <hip/hip_runtime.h>
#include <math.h>

#define N_PTS 8192
#define KFULL 40
#define KNB 20
#define QB 8
#define NBUCK 2048
#define CAP 512

typedef unsigned short u16;
typedef __attribute__((ext_vector_type(8))) short bf16x8;
typedef __attribute__((ext_vector_type(4))) float f32x4;

__device__ __forceinline__ u16 f2b(float v) {  // RNE float->bf16 bits
  unsigned int u = __float_as_uint(v);
  return (u16)((u + 0x7FFFu + ((u >> 16) & 1u)) >> 16);
}

typedef const __attribute__((address_space(1))) unsigned int* gas_p;
typedef __attribute__((address_space(3))) unsigned int* las_p;
__device__ __forceinline__ void gll16(const void* g, void* l) {
  __builtin_amdgcn_global_load_lds((gas_p)g, (las_p)l, 16, 0, 0);
}

// ---------------------------------------------------------------------------
// sq[j] = |p_j|^2
// ---------------------------------------------------------------------------
__global__ __launch_bounds__(256) void sq_kernel(const float* __restrict__ pos,
                                                 float* __restrict__ sq) {
  const int j = blockIdx.x * 256 + threadIdx.x;
  const float x = pos[j * 3 + 0], y = pos[j * 3 + 1], z = pos[j * 3 + 2];
  sq[j] = x * x + y * y + z * z;
}

// ---------------------------------------------------------------------------
// kNN v3: 8 queries per block, histogram select with packed u16 counters.
// Self is included (rank 0) and dropped; ranks 1..40 are written.
// ---------------------------------------------------------------------------
__global__ __launch_bounds__(256) void knn_kernel(const float* __restrict__ pos,
                                                  const float* __restrict__ sq,
                                                  int* __restrict__ idx_out) {
  __shared__ __align__(16) unsigned int histmem[4 * NBUCK];  // 32 KB
  unsigned int (*hist)[NBUCK] = (unsigned int(*)[NBUCK])histmem;
  unsigned long long (*cand)[CAP] = (unsigned long long(*)[CAP])histmem;
  __shared__ float s_q[QB][4];
  __shared__ int s_bstar[QB];
  __shared__ int s_cnt[QB];

  const int qbase = blockIdx.x * QB;
  const int t = threadIdx.x;

  for (int b = t; b < 4 * NBUCK; b += 256) histmem[b] = 0;
  if (t < QB) {
    s_cnt[t] = 0;
    const int q = qbase + t;
    s_q[t][0] = pos[q * 3 + 0];
    s_q[t][1] = pos[q * 3 + 1];
    s_q[t][2] = pos[q * 3 + 2];
    s_q[t][3] = sq[q];
  }
  __syncthreads();

  float qx[QB], qy[QB], qz[QB], qs[QB];
#pragma unroll
  for (int q = 0; q < QB; ++q) {
    qx[q] = s_q[q][0]; qy[q] = s_q[q][1]; qz[q] = s_q[q][2]; qs[q] = s_q[q][3];
  }

  // ---- pass 1: packed histograms ----
#pragma unroll
  for (int s = 0; s < 32; ++s) {
    const int j = t + (s << 8);
    const float x = pos[j * 3 + 0], y = pos[j * 3 + 1], z = pos[j * 3 + 2];
    const float sj = sq[j];
#pragma unroll
    for (int q = 0; q < QB; ++q) {
      const float dt = qx[q] * x + qy[q] * y + qz[q] * z;
      const float d = (qs[q] + sj) - 2.0f * dt;
      unsigned int b = __float_as_uint(d);
      b = b ^ ((unsigned int)(((int)b) >> 31) | 0x80000000u);
      atomicAdd(&hist[q >> 1][b >> 21], 1u << ((q & 1) * 16));
    }
  }
  __syncthreads();

  // ---- scan: wave w handles packed array w (queries 2w, 2w+1) ----
  {
    const int w = t >> 6, lane = t & 63;
    const int b0 = lane * (NBUCK / 64);
    unsigned int lsum = 0;
#pragma unroll
    for (int b = 0; b < NBUCK / 64; ++b) lsum += hist[w][b0 + b];
    unsigned int inc = lsum;  // packed scan: each half < 2^15, no carry cross
#pragma unroll
    for (int off = 1; off < 64; off <<= 1) {
      const unsigned int u = __shfl_up(inc, off);
      if (lane >= off) inc += u;
    }
    const unsigned int excl = inc - lsum;
    const unsigned int TGT = KFULL + 1;  // 41 incl. self
    const unsigned int exlo = excl & 0xFFFFu, inlo = inc & 0xFFFFu;
    const unsigned int exhi = excl >> 16, inhi = inc >> 16;
    if (exlo < TGT && inlo >= TGT) {
      unsigned int cum = exlo;
      int b = 0;
      for (; b < NBUCK / 64; ++b) {
        cum += hist[w][b0 + b] & 0xFFFFu;
        if (cum >= TGT) break;
      }
      s_bstar[2 * w] = b0 + b;
    }
    if (exhi < TGT && inhi >= TGT) {
      unsigned int cum = exhi;
      int b = 0;
      for (; b < NBUCK / 64; ++b) {
        cum += hist[w][b0 + b] >> 16;
        if (cum >= TGT) break;
      }
      s_bstar[2 * w + 1] = b0 + b;
    }
  }
  __syncthreads();
  unsigned int bst[QB];
#pragma unroll
  for (int q = 0; q < QB; ++q) bst[q] = (unsigned int)s_bstar[q];
  __syncthreads();  // scan reads done; histmem now reused as cand

  // ---- pass 2: compact candidates ----
#pragma unroll
  for (int s = 0; s < 32; ++s) {
    const int j = t + (s << 8);
    const float x = pos[j * 3 + 0], y = pos[j * 3 + 1], z = pos[j * 3 + 2];
    const float sj = sq[j];
#pragma unroll
    for (int q = 0; q < QB; ++q) {
      const float dt = qx[q] * x + qy[q] * y + qz[q] * z;
      const float d = (qs[q] + sj) - 2.0f * dt;
      unsigned int b = __float_as_uint(d);
      b = b ^ ((unsigned int)(((int)b) >> 31) | 0x80000000u);
      if ((b >> 21) <= bst[q]) {
        const int slot = atomicAdd(&s_cnt[q], 1);
        if (slot < CAP)
          cand[q][slot] = ((unsigned long long)b << 13) | (unsigned long long)j;
      }
    }
  }
  __syncthreads();

  // ---- rank sort: wave w sorts queries 2w and 2w+1 ----
  {
    const int w = t >> 6, lane = t & 63;
#pragma unroll
    for (int hh = 0; hh < 2; ++hh) {
      const int q = 2 * w + hh;
      const int cnt = s_cnt[q] < CAP ? s_cnt[q] : CAP;
      for (int c0 = lane; c0 < cnt; c0 += 64) {
        const unsigned long long my = cand[q][c0];
        int rank = 0;
        for (int c = 0; c < cnt; ++c) rank += (cand[q][c] < my) ? 1 : 0;
        if (rank >= 1 && rank <= KFULL)
          idx_out[(qbase + q) * KFULL + (rank - 1)] = (int)(my & 0x1FFFull);
      }
    }
  }
}

// ---------------------------------------------------------------------------
// Lift: A0 = pos @ W0[0:3] + b0 ; P0 = pos @ W0[3:6]  -> AP0 [N, 256] (f32)
// ---------------------------------------------------------------------------
__global__ __launch_bounds__(128) void lift_kernel(const float* __restrict__ pos,
                                                   const float* __restrict__ W0,
                                                   const float* __restrict__ b0,
                                                   float* __restrict__ AP0) {
  const int i = blockIdx.x;
  const int c = threadIdx.x;
  const float px = pos[i * 3 + 0], py = pos[i * 3 + 1], pz = pos[i * 3 + 2];
  const float a = b0[c] + px * W0[c] + py * W0[128 + c] + pz * W0[256 + c];
  const float p = px * W0[384 + c] + py * W0[512 + c] + pz * W0[640 + c];
  AP0[(size_t)i * 256 + c] = a;
  AP0[(size_t)i * 256 + 128 + c] = p;
}

// ---------------------------------------------------------------------------
// Weight convert+transpose to bf16 [n][k]: for tensor li, dst row r:
// part = r/ncols (top/bottom K-panel), col = r%ncols;
// dst[r][k] = src[(part*128 + k)*ncols + col]
// ---------------------------------------------------------------------------
__global__ __launch_bounds__(128) void wcvt_kernel(const float* __restrict__ src,
                                                   u16* __restrict__ dst, int ncols,
                                                   int rows_per_tensor,
                                                   int elems_per_tensor) {
  const int rg = blockIdx.x;
  const int li = rg / rows_per_tensor;
  const int r = rg % rows_per_tensor;
  const int k = threadIdx.x;
  const float* s = src + (size_t)li * elems_per_tensor;
  u16* d = dst + (size_t)li * elems_per_tensor;
  const int part = r / ncols, col = r % ncols;
  d[(size_t)r * 128 + k] = f2b(s[(size_t)(part * 128 + k) * ncols + col]);
}

// ---------------------------------------------------------------------------
// bf16 MFMA GEMM: out[m,n] = act(A[m,:] @ Wt[n,:] + bias[n<NA]), K=128.
// BM=128, BN=64, 4 waves. A [M][128] bf16, Wt [Ntot][128] bf16 (pre-transposed).
// Staging: global_load_lds 16B, linear LDS dest + inverse-XOR-swizzled source;
// ds_read_b128 with matching swizzle (chunk ^= row&7).
// ---------------------------------------------------------------------------
__global__ __launch_bounds__(256) void gemm_mfma_kernel(
    const u16* __restrict__ A, const u16* __restrict__ Wt,
    const float* __restrict__ bias, int NA, int Ntot, float slope, int use_act,
    float* __restrict__ out) {
  __shared__ __align__(16) u16 Al[128 * 128];  // 32 KB
  __shared__ __align__(16) u16 Bl[64 * 128];   // 16 KB
  const int bm = blockIdx.x * 128;
  const int bn = blockIdx.y * 64;
  const int tid = threadIdx.x;

#pragma unroll
  for (int it = 0; it < 8; ++it) {
    const int g = it * 256 + tid;  // 16B chunk id: row = g>>4, chunk c = g&15
    const int row = g >> 4, c = g & 15;
    const int sc = c ^ (row & 7);
    gll16(A + (size_t)(bm + row) * 128 + sc * 8, &Al[g * 8]);
  }
#pragma unroll
  for (int it = 0; it < 4; ++it) {
    const int g = it * 256 + tid;
    const int row = g >> 4, c = g & 15;
    const int sc = c ^ (row & 7);
    gll16(Wt + (size_t)(bn + row) * 128 + sc * 8, &Bl[g * 8]);
  }
  __syncthreads();  // drains vmcnt before barrier

  const int wv = tid >> 6, lane = tid & 63;
  const int wm = wv & 1, wn = wv >> 1;      // wave tile: 64 rows x 32 cols
  const int lr = lane & 15, lk = lane >> 4;  // frag row/col, k-group

  bf16x8 a[4][4], b[2][4];
  f32x4 acc[4][2];
#pragma unroll
  for (int m = 0; m < 4; ++m)
#pragma unroll
    for (int n = 0; n < 2; ++n) acc[m][n] = (f32x4){0.f, 0.f, 0.f, 0.f};

#pragma unroll
  for (int m = 0; m < 4; ++m) {
    const int row = wm * 64 + m * 16 + lr;
#pragma unroll
    for (int ks = 0; ks < 4; ++ks) {
      const int c = ks * 4 + lk;
      a[m][ks] = *(const bf16x8*)&Al[row * 128 + (c ^ (row & 7)) * 8];
    }
  }
#pragma unroll
  for (int n = 0; n < 2; ++n) {
    const int col = wn * 32 + n * 16 + lr;
#pragma unroll
    for (int ks = 0; ks < 4; ++ks) {
      const int c = ks * 4 + lk;
      b[n][ks] = *(const bf16x8*)&Bl[col * 128 + (c ^ (col & 7)) * 8];
    }
  }

#pragma unroll
  for (int ks = 0; ks < 4; ++ks)
#pragma unroll
    for (int m = 0; m < 4; ++m)
#pragma unroll
      for (int n = 0; n < 2; ++n)
        acc[m][n] = __builtin_amdgcn_mfma_f32_16x16x32_bf16(a[m][ks], b[n][ks],
                                                            acc[m][n], 0, 0, 0);

  // C/D: col = lane&15, row = (lane>>4)*4 + reg   [m89-verified]
#pragma unroll
  for (int n = 0; n < 2; ++n) {
    const int col = bn + wn * 32 + n * 16 + lr;
    float bv = 0.f;
    if (col < NA) bv = bias[col];
#pragma unroll
    for (int m = 0; m < 4; ++m) {
      const int row0 = bm + wm * 64 + m * 16 + lk * 4;
#pragma unroll
      for (int r = 0; r < 4; ++r) {
        float v = acc[m][n][r] + bv;
        if (use_act) v = v > 0.f ? v : v * slope;
        out[(size_t)(row0 + r) * Ntot + col] = v;
      }
    }
  }
}

// ---------------------------------------------------------------------------
// Gather-max + combine: v = LR(A[i,c] - P[i,c] + max_j P[nbr_j, c], 0.2)
// Writes f32 and/or bf16 outputs (null skips).
// ---------------------------------------------------------------------------
__global__ __launch_bounds__(128) void gather_max_kernel(
    const float* __restrict__ AP, const int* __restrict__ idx, int Ntot, int NA,
    int dil, float* __restrict__ out_f32, u16* __restrict__ out_b16) {
  const int i = blockIdx.x;
  const int c = blockIdx.y * 128 + threadIdx.x;
  const float* P = AP + NA;
  float m = -INFINITY;
#pragma unroll
  for (int j = 0; j < KNB; ++j) {
    const int n = idx[i * KFULL + j * dil];
    m = fmaxf(m, P[(size_t)n * Ntot + c]);
  }
  const float a = AP[(size_t)i * Ntot + c];
  const float p = P[(size_t)i * Ntot + c];
  float v = a - p + m;
  v = v > 0.f ? v : 0.2f * v;
  if (out_f32) out_f32[(size_t)i * NA + c] = v;
  if (out_b16) out_b16[(size_t)i * NA + c] = f2b(v);
}

// residual: h += 0.5*(B1+B2); also emit bf16 shadow
__global__ __launch_bounds__(256) void combine_kernel(float* __restrict__ h,
                                                      const float* __restrict__ B1,
                                                      const float* __restrict__ B2,
                                                      u16* __restrict__ hb) {
  const int i = blockIdx.x * 256 + threadIdx.x;
  const float v = h[i] + 0.5f * (B1[i] + B2[i]);
  h[i] = v;
  hb[i] = f2b(v);
}

// ---------------------------------------------------------------------------
// Final projection: q = T @ Wr2 + br2   (T: [32768,128], Wr2: [128,3])
// ---------------------------------------------------------------------------
__global__ __launch_bounds__(128) void recon2_kernel(const float* __restrict__ T,
                                                     const float* __restrict__ Wr2,
                                                     const float* __restrict__ br2,
                                                     float* __restrict__ out) {
  __shared__ float tile[32][129];
  __shared__ float w2[384];
  const int tid = threadIdx.x;
  const int r0 = blockIdx.x * 32;
  w2[tid] = Wr2[tid];
  w2[tid + 128] = Wr2[tid + 128];
  w2[tid + 256] = Wr2[tid + 256];
  for (int s = 0; s < 32; ++s) tile[s][tid] = T[(size_t)(r0 + s) * 128 + tid];
  __syncthreads();
  if (tid < 96) {
    const int r = tid / 3, n = tid % 3;
    float acc = br2[n];
#pragma unroll
    for (int k = 0; k < 128; ++k) acc = fmaf(tile[r][k], w2[k * 3 + n], acc);
    out[(size_t)(r0 + r) * 3 + n] = acc;
  }
}

// ---------------------------------------------------------------------------
extern "C" void kernel_launch(void* const* d_in, const int* in_sizes, int n_in,
                              void* d_out, int out_size, void* d_ws, size_t ws_size,
                              hipStream_t stream) {
  const float* x = (const float*)d_in[0];
  const float* W0 = (const float*)d_in[1];
  const float* b0 = (const float*)d_in[2];
  const float* Wg = (const float*)d_in[3];
  const float* bg = (const float*)d_in[4];
  const float* Wu = (const float*)d_in[5];
  const float* bu = (const float*)d_in[6];
  const float* Wr1 = (const float*)d_in[7];
  const float* br1 = (const float*)d_in[8];
  const float* Wr2 = (const float*)d_in[9];
  const float* br2 = (const float*)d_in[10];
  float* out = (float*)d_out;

  char* w = (char*)d_ws;
  int* idx = (int*)(w + 0);             // 1,310,720
  float* sq = (float*)(w + 1310720);    // 32,768
  float* h = (float*)(w + 1343488);     // 4 MB
  u16* hb = (u16*)(w + 5537792);        // 2 MB
  float* B1 = (float*)(w + 7634944);    // 4 MB
  float* B2 = (float*)(w + 11829248);   // 4 MB
  u16* Ub = (u16*)(w + 16023552);       // 8 MB
  u16* Wgb = (u16*)(w + 24412160);      // 256 KB
  u16* Wub = (u16*)(w + 24674304);      // 256 KB
  u16* Wr1b = (u16*)(w + 24936448);     // 32 KB
  float* AP = (float*)(w + 24969216);   // 32 MB
  float* T = AP;                        // recon1 out aliases AP

  // weight conversion (transpose to [n][k] bf16)
  wcvt_kernel<<<1024, 128, 0, stream>>>(Wg, Wgb, 128, 256, 256 * 128);
  wcvt_kernel<<<1024, 128, 0, stream>>>(Wu, Wub, 512, 1024, 1024 * 128);
  wcvt_kernel<<<128, 128, 0, stream>>>(Wr1, Wr1b, 128, 128, 128 * 128);

  sq_kernel<<<32, 256, 0, stream>>>(x, sq);
  knn_kernel<<<N_PTS / QB, 256, 0, stream>>>(x, sq, idx);

  // lift 3 -> 128 (factorized EdgeConv), first h
  lift_kernel<<<N_PTS, 128, 0, stream>>>(x, W0, b0, AP);
  gather_max_kernel<<<dim3(N_PTS, 1), 128, 0, stream>>>(AP, idx, 256, 128, 1, h, hb);

  // 2 inception blocks x 2 dilated branches
  for (int li = 0; li < 4; ++li) {
    gemm_mfma_kernel<<<dim3(64, 4), 256, 0, stream>>>(
        hb, Wgb + (size_t)li * 256 * 128, bg + li * 128, 128, 256, 0.f, 0, AP);
    const int dil = (li & 1) ? 2 : 1;
    float* Bd = (li & 1) ? B2 : B1;
    gather_max_kernel<<<dim3(N_PTS, 1), 128, 0, stream>>>(AP, idx, 256, 128, dil,
                                                          Bd, (u16*)nullptr);
    if (li & 1)
      combine_kernel<<<4096, 256, 0, stream>>>(h, B1, B2, hb);
  }

  // NodeShuffle upsampler: EdgeConv to r*C=512 (reshape free, row-major)
  gemm_mfma_kernel<<<dim3(64, 16), 256, 0, stream>>>(hb, Wub, bu, 512, 1024, 0.f,
                                                     0, AP);
  gather_max_kernel<<<dim3(N_PTS, 4), 128, 0, stream>>>(AP, idx, 1024, 512, 1,
                                                        (float*)nullptr, Ub);

  // reconstructor MLP
  gemm_mfma_kernel<<<dim3(256, 2), 256, 0, stream>>>(Ub, Wr1b, br1, 128, 128,
                                                     0.01f, 1, T);
  recon2_kernel<<<1024, 128, 0, stream>>>(T, Wr2, br2, out);
}

// Round 4
// 178.131 us; speedup vs baseline: 3.4322x; 1.4004x over previous
//
#include <hip/hip_runtime.h>
#include <math.h>

#define N_PTS 8192
#define KFULL 40
#define KNB 20
#define QB 8
#define NBUCK 1024
#define HWORDS (NBUCK + NBUCK / 16)  // 1088, +1-per-16 padding (bank-conflict-free scan)
#define CAP 384

typedef unsigned short u16;
typedef unsigned int u32;
typedef unsigned long long u64;
typedef __attribute__((ext_vector_type(8))) short bf16x8;
typedef __attribute__((ext_vector_type(4))) float f32x4;

__device__ __forceinline__ u16 f2b(float v) {  // RNE float->bf16 bits
  u32 u = __float_as_uint(v);
  return (u16)((u + 0x7FFFu + ((u >> 16) & 1u)) >> 16);
}
__device__ __forceinline__ u32 pk2(float a, float b) {
  return (u32)f2b(a) | ((u32)f2b(b) << 16);
}
__device__ __forceinline__ u32 dmap(float d) {  // order-preserving float->u32
  u32 b = __float_as_uint(d);
  return b ^ ((u32)(((int)b) >> 31) | 0x80000000u);
}
__device__ __forceinline__ void maxu4(const uint4 v, float m[8]) {
  m[0] = fmaxf(m[0], __uint_as_float(v.x << 16));
  m[1] = fmaxf(m[1], __uint_as_float(v.x & 0xFFFF0000u));
  m[2] = fmaxf(m[2], __uint_as_float(v.y << 16));
  m[3] = fmaxf(m[3], __uint_as_float(v.y & 0xFFFF0000u));
  m[4] = fmaxf(m[4], __uint_as_float(v.z << 16));
  m[5] = fmaxf(m[5], __uint_as_float(v.z & 0xFFFF0000u));
  m[6] = fmaxf(m[6], __uint_as_float(v.w << 16));
  m[7] = fmaxf(m[7], __uint_as_float(v.w & 0xFFFF0000u));
}
__device__ __forceinline__ void unp4(const uint4 v, float p[8]) {
  p[0] = __uint_as_float(v.x << 16);
  p[1] = __uint_as_float(v.x & 0xFFFF0000u);
  p[2] = __uint_as_float(v.y << 16);
  p[3] = __uint_as_float(v.y & 0xFFFF0000u);
  p[4] = __uint_as_float(v.z << 16);
  p[5] = __uint_as_float(v.z & 0xFFFF0000u);
  p[6] = __uint_as_float(v.w << 16);
  p[7] = __uint_as_float(v.w & 0xFFFF0000u);
}

typedef const __attribute__((address_space(1))) unsigned int* gas_p;
typedef __attribute__((address_space(3))) unsigned int* las_p;
__device__ __forceinline__ void gll16(const void* g, void* l) {
  __builtin_amdgcn_global_load_lds((gas_p)g, (las_p)l, 16, 0, 0);
}

// ---------------------------------------------------------------------------
// pos4[j] = (x, y, z, |p|^2)
// ---------------------------------------------------------------------------
__global__ __launch_bounds__(256) void pos4_kernel(const float* __restrict__ pos,
                                                   float4* __restrict__ pos4) {
  const int j = blockIdx.x * 256 + threadIdx.x;
  const float x = pos[j * 3 + 0], y = pos[j * 3 + 1], z = pos[j * 3 + 2];
  pos4[j] = make_float4(x, y, z, x * x + y * y + z * z);
}

// ---------------------------------------------------------------------------
// scan over padded packed histograms: find bucket where cumulative >= 41.
// Wave w handles hist[w] (queries 2w lo16, 2w+1 hi16).
// ---------------------------------------------------------------------------
__device__ __forceinline__ void scan_cut(const u32 (*hist)[HWORDS], int* s_cut,
                                         int t) {
  const int w = t >> 6, lane = t & 63;
  const u32* H = hist[w];
  const int base = lane * 17;
  u32 lsum = 0;
#pragma unroll
  for (int k = 0; k < 16; ++k) lsum += H[base + k];
  u32 inc = lsum;
#pragma unroll
  for (int off = 1; off < 64; off <<= 1) {
    const u32 u = __shfl_up(inc, off);
    if (lane >= off) inc += u;
  }
  const u32 excl = inc - lsum;
  const u32 TGT = KFULL + 1;  // 41 incl. self
  const u32 exlo = excl & 0xFFFFu, inlo = inc & 0xFFFFu;
  if (exlo < TGT && inlo >= TGT) {
    u32 cum = exlo;
    for (int k = 0; k < 16; ++k) {
      cum += H[base + k] & 0xFFFFu;
      if (cum >= TGT) { s_cut[2 * w] = lane * 16 + k; break; }
    }
  }
  const u32 exhi = excl >> 16, inhi = inc >> 16;
  if (exhi < TGT && inhi >= TGT) {
    u32 cum = exhi;
    for (int k = 0; k < 16; ++k) {
      cum += H[base + k] >> 16;
      if (cum >= TGT) { s_cut[2 * w + 1] = lane * 16 + k; break; }
    }
  }
}

// ---------------------------------------------------------------------------
// kNN v4: 8 queries/block. Phase 0: 512-point subsample -> upper-bound bucket
// (subset 41st >= full 41st). Pass 1: histogram only points <= that bound.
// Pass 2: compact shell <= exact cutoff. Rank-sort with (dist|idx) keys.
// ---------------------------------------------------------------------------
__global__ __launch_bounds__(256) void knn_kernel(const float4* __restrict__ pos4,
                                                  int* __restrict__ idx_out) {
  __shared__ __align__(16) u32 hmem[CAP * QB * 2];  // 24576 B >= 4*HWORDS
  u32 (*hist)[HWORDS] = (u32(*)[HWORDS])hmem;
  u64 (*cand)[CAP] = (u64(*)[CAP])hmem;
  __shared__ float4 s_q[QB];
  __shared__ int s_cut[QB];
  __shared__ int s_cnt[QB];

  const int qb = blockIdx.x * QB, t = threadIdx.x;
  if (t < QB) {
    s_q[t] = pos4[qb + t];
    s_cnt[t] = 0;
  }
  for (int b = t; b < 4 * HWORDS; b += 256) hmem[b] = 0;
  __syncthreads();

  float qx[QB], qy[QB], qz[QB], qs[QB];
#pragma unroll
  for (int q = 0; q < QB; ++q) {
    const float4 v = s_q[q];
    qx[q] = -2.0f * v.x; qy[q] = -2.0f * v.y; qz[q] = -2.0f * v.z; qs[q] = v.w;
  }

  // ---- phase 0: subsample (stride 16) histogram ----
#pragma unroll
  for (int k = 0; k < 2; ++k) {
    const int j = (t + (k << 8)) << 4;
    const float4 p = pos4[j];
#pragma unroll
    for (int q = 0; q < QB; ++q) {
      const float d = fmaf(qx[q], p.x, fmaf(qy[q], p.y, fmaf(qz[q], p.z, qs[q] + p.w)));
      const u32 bk = dmap(d) >> 22;
      atomicAdd(&hist[q >> 1][bk + (bk >> 4)], 1u << ((q & 1) * 16));
    }
  }
  __syncthreads();
  scan_cut(hist, s_cut, t);
  __syncthreads();
  int bcut[QB];
#pragma unroll
  for (int q = 0; q < QB; ++q) bcut[q] = s_cut[q];
  for (int b = t; b < 4 * HWORDS; b += 256) hmem[b] = 0;
  __syncthreads();

  // ---- pass 1: filtered histogram ----
  for (int s = 0; s < 32; ++s) {
    const int j = t + (s << 8);
    const float4 p = pos4[j];
#pragma unroll
    for (int q = 0; q < QB; ++q) {
      const float d = fmaf(qx[q], p.x, fmaf(qy[q], p.y, fmaf(qz[q], p.z, qs[q] + p.w)));
      const u32 bk = dmap(d) >> 22;
      if ((int)bk <= bcut[q])
        atomicAdd(&hist[q >> 1][bk + (bk >> 4)], 1u << ((q & 1) * 16));
    }
  }
  __syncthreads();
  scan_cut(hist, s_cut, t);
  __syncthreads();
#pragma unroll
  for (int q = 0; q < QB; ++q) bcut[q] = s_cut[q];
  __syncthreads();  // hist reads done; hmem reused as cand below

  // ---- pass 2: compact shell ----
  for (int s = 0; s < 32; ++s) {
    const int j = t + (s << 8);
    const float4 p = pos4[j];
#pragma unroll
    for (int q = 0; q < QB; ++q) {
      const float d = fmaf(qx[q], p.x, fmaf(qy[q], p.y, fmaf(qz[q], p.z, qs[q] + p.w)));
      const u32 mp = dmap(d);
      if ((int)(mp >> 22) <= bcut[q]) {
        const int slot = atomicAdd(&s_cnt[q], 1);
        if (slot < CAP) cand[q][slot] = ((u64)mp << 13) | (u64)j;
      }
    }
  }
  __syncthreads();

  // ---- rank sort (self = rank 0, dropped) ----
  {
    const int w = t >> 6, lane = t & 63;
#pragma unroll
    for (int hh = 0; hh < 2; ++hh) {
      const int q = 2 * w + hh;
      const int cnt = s_cnt[q] < CAP ? s_cnt[q] : CAP;
      for (int c0 = lane; c0 < cnt; c0 += 64) {
        const u64 my = cand[q][c0];
        int rank = 0;
        for (int c = 0; c < cnt; ++c) rank += (cand[q][c] < my) ? 1 : 0;
        if (rank >= 1 && rank <= KFULL)
          idx_out[(qb + q) * KFULL + (rank - 1)] = (int)(my & 0x1FFFull);
      }
    }
  }
}

// ---------------------------------------------------------------------------
// Lift: A = pos @ W0[0:3] + b0 (f32) ; P = pos @ W0[3:6] (bf16)
// ---------------------------------------------------------------------------
__global__ __launch_bounds__(128) void lift_kernel(const float* __restrict__ pos,
                                                   const float* __restrict__ W0,
                                                   const float* __restrict__ b0,
                                                   float* __restrict__ Aout,
                                                   u16* __restrict__ Pout) {
  const int i = blockIdx.x;
  const int c = threadIdx.x;
  const float px = pos[i * 3 + 0], py = pos[i * 3 + 1], pz = pos[i * 3 + 2];
  const float a = b0[c] + px * W0[c] + py * W0[128 + c] + pz * W0[256 + c];
  const float p = px * W0[384 + c] + py * W0[512 + c] + pz * W0[640 + c];
  Aout[(size_t)i * 128 + c] = a;
  Pout[(size_t)i * 128 + c] = f2b(p);
}

// ---------------------------------------------------------------------------
// Weight convert+transpose to bf16 [n][k]
// ---------------------------------------------------------------------------
__global__ __launch_bounds__(128) void wcvt_kernel(const float* __restrict__ src,
                                                   u16* __restrict__ dst, int ncols,
                                                   int rows_per_tensor,
                                                   int elems_per_tensor) {
  const int rg = blockIdx.x;
  const int li = rg / rows_per_tensor;
  const int r = rg % rows_per_tensor;
  const int k = threadIdx.x;
  const float* s = src + (size_t)li * elems_per_tensor;
  u16* d = dst + (size_t)li * elems_per_tensor;
  const int part = r / ncols, col = r % ncols;
  d[(size_t)r * 128 + k] = f2b(s[(size_t)(part * 128 + k) * ncols + col]);
}

// ---------------------------------------------------------------------------
// bf16 MFMA GEMM, K=128, BM=128, BN=64. Epilogue splits per-group cols into
// A (f32, +bias, opt act) and P (bf16).
// ---------------------------------------------------------------------------
__global__ __launch_bounds__(256) void gemm_mfma_kernel(
    const u16* __restrict__ Ain, const u16* __restrict__ Wt,
    const float* __restrict__ bias, int GA, int span_shift, int nAtot, int nPtot,
    float slope, int use_act, float* __restrict__ Aout, u16* __restrict__ Pout) {
  __shared__ __align__(16) u16 Al[128 * 128];
  __shared__ __align__(16) u16 Bl[64 * 128];
  const int bm = blockIdx.x * 128;
  const int bn = blockIdx.y * 64;
  const int tid = threadIdx.x;

#pragma unroll
  for (int it = 0; it < 8; ++it) {
    const int g = it * 256 + tid;
    const int row = g >> 4, cc = g & 15;
    const int sc = cc ^ (row & 7);
    gll16(Ain + (size_t)(bm + row) * 128 + sc * 8, &Al[g * 8]);
  }
#pragma unroll
  for (int it = 0; it < 4; ++it) {
    const int g = it * 256 + tid;
    const int row = g >> 4, cc = g & 15;
    const int sc = cc ^ (row & 7);
    gll16(Wt + (size_t)(bn + row) * 128 + sc * 8, &Bl[g * 8]);
  }
  __syncthreads();

  const int wv = tid >> 6, lane = tid & 63;
  const int wm = wv & 1, wn = wv >> 1;
  const int lr = lane & 15, lk = lane >> 4;

  bf16x8 a[4][4], b[2][4];
  f32x4 acc[4][2];
#pragma unroll
  for (int m = 0; m < 4; ++m)
#pragma unroll
    for (int n = 0; n < 2; ++n) acc[m][n] = (f32x4){0.f, 0.f, 0.f, 0.f};

#pragma unroll
  for (int m = 0; m < 4; ++m) {
    const int row = wm * 64 + m * 16 + lr;
#pragma unroll
    for (int ks = 0; ks < 4; ++ks) {
      const int c = ks * 4 + lk;
      a[m][ks] = *(const bf16x8*)&Al[row * 128 + (c ^ (row & 7)) * 8];
    }
  }
#pragma unroll
  for (int n = 0; n < 2; ++n) {
    const int col = wn * 32 + n * 16 + lr;
#pragma unroll
    for (int ks = 0; ks < 4; ++ks) {
      const int c = ks * 4 + lk;
      b[n][ks] = *(const bf16x8*)&Bl[col * 128 + (c ^ (col & 7)) * 8];
    }
  }

#pragma unroll
  for (int ks = 0; ks < 4; ++ks)
#pragma unroll
    for (int m = 0; m < 4; ++m)
#pragma unroll
      for (int n = 0; n < 2; ++n)
        acc[m][n] = __builtin_amdgcn_mfma_f32_16x16x32_bf16(a[m][ks], b[n][ks],
                                                            acc[m][n], 0, 0, 0);

  const int span = 1 << span_shift;
  const int GP = span - GA;
#pragma unroll
  for (int n = 0; n < 2; ++n) {
    const int col = bn + wn * 32 + n * 16 + lr;
    const int g = col >> span_shift;
    const int wi = col & (span - 1);
    const bool isA = wi < GA;
    const float bv = isA ? bias[g * GA + wi] : 0.f;
#pragma unroll
    for (int m = 0; m < 4; ++m) {
      const int row0 = bm + wm * 64 + m * 16 + lk * 4;
#pragma unroll
      for (int r = 0; r < 4; ++r) {
        float v = acc[m][n][r] + bv;
        if (isA) {
          if (use_act) v = v > 0.f ? v : v * slope;
          Aout[(size_t)(row0 + r) * nAtot + g * GA + wi] = v;
        } else {
          Pout[(size_t)(row0 + r) * nPtot + g * GP + (wi - GA)] = f2b(v);
        }
      }
    }
  }
}

// ---------------------------------------------------------------------------
// Single-branch gather-max: out = LR(A - P_self + max_j P[nbr_j], 0.2).
// 16 queries x 128 cols per block; P bf16 gathered as uint4 (8 cols/thread).
// ---------------------------------------------------------------------------
__global__ __launch_bounds__(256) void gather_one_kernel(
    const float* __restrict__ A, const u16* __restrict__ P,
    const int* __restrict__ idx, int C, int dil, float* __restrict__ outf,
    u16* __restrict__ outb) {
  const int t = threadIdx.x;
  const int i = blockIdx.x * 16 + (t >> 4);
  const int c = blockIdx.y * 128 + (t & 15) * 8;
  float m[8];
#pragma unroll
  for (int k = 0; k < 8; ++k) m[k] = -INFINITY;
  const int ib = i * KFULL;
#pragma unroll
  for (int j = 0; j < KNB; ++j) {
    const int n = idx[ib + j * dil] & (N_PTS - 1);
    maxu4(*(const uint4*)&P[(size_t)n * C + c], m);
  }
  float pv[8];
  unp4(*(const uint4*)&P[(size_t)i * C + c], pv);
  const float4 a0 = *(const float4*)&A[(size_t)i * C + c];
  const float4 a1 = *(const float4*)&A[(size_t)i * C + c + 4];
  const float av[8] = {a0.x, a0.y, a0.z, a0.w, a1.x, a1.y, a1.z, a1.w};
  float v[8];
#pragma unroll
  for (int k = 0; k < 8; ++k) {
    const float x = av[k] - pv[k] + m[k];
    v[k] = x > 0.f ? x : 0.2f * x;
  }
  if (outf) {
    *(float4*)&outf[(size_t)i * C + c] = make_float4(v[0], v[1], v[2], v[3]);
    *(float4*)&outf[(size_t)i * C + c + 4] = make_float4(v[4], v[5], v[6], v[7]);
  }
  if (outb) {
    uint4 pb = {pk2(v[0], v[1]), pk2(v[2], v[3]), pk2(v[4], v[5]), pk2(v[6], v[7])};
    *(uint4*)&outb[(size_t)i * C + c] = pb;
  }
}

// ---------------------------------------------------------------------------
// Fused inception pair: h += 0.5*(LR(A0-P0+max_dil1 P0) + LR(A1-P1+max_dil2 P1))
// Apair [N][256] f32 (A0|A1), Ppair [N][256] bf16 (P0|P1). Writes h f32 + hb.
// ---------------------------------------------------------------------------
__global__ __launch_bounds__(256) void gather_pair_kernel(
    const float* __restrict__ Ap, const u16* __restrict__ Pp,
    const int* __restrict__ idx, float* __restrict__ h, u16* __restrict__ hb) {
  const int t = threadIdx.x;
  const int i = blockIdx.x * 16 + (t >> 4);
  const int c = (t & 15) * 8;
  float m1[8], m2[8];
#pragma unroll
  for (int k = 0; k < 8; ++k) { m1[k] = -INFINITY; m2[k] = -INFINITY; }
  const int ib = i * KFULL;
#pragma unroll
  for (int j = 0; j < KNB; ++j) {
    const int n1 = idx[ib + j] & (N_PTS - 1);
    maxu4(*(const uint4*)&Pp[(size_t)n1 * 256 + c], m1);
    const int n2 = idx[ib + 2 * j] & (N_PTS - 1);
    maxu4(*(const uint4*)&Pp[(size_t)n2 * 256 + 128 + c], m2);
  }
  float p0[8], p1[8];
  unp4(*(const uint4*)&Pp[(size_t)i * 256 + c], p0);
  unp4(*(const uint4*)&Pp[(size_t)i * 256 + 128 + c], p1);
  const float4 a00 = *(const float4*)&Ap[(size_t)i * 256 + c];
  const float4 a01 = *(const float4*)&Ap[(size_t)i * 256 + c + 4];
  const float4 a10 = *(const float4*)&Ap[(size_t)i * 256 + 128 + c];
  const float4 a11 = *(const float4*)&Ap[(size_t)i * 256 + 128 + c + 4];
  const float av0[8] = {a00.x, a00.y, a00.z, a00.w, a01.x, a01.y, a01.z, a01.w};
  const float av1[8] = {a10.x, a10.y, a10.z, a10.w, a11.x, a11.y, a11.z, a11.w};
  const float4 h0 = *(const float4*)&h[(size_t)i * 128 + c];
  const float4 h1 = *(const float4*)&h[(size_t)i * 128 + c + 4];
  const float hv[8] = {h0.x, h0.y, h0.z, h0.w, h1.x, h1.y, h1.z, h1.w};
  float v[8];
#pragma unroll
  for (int k = 0; k < 8; ++k) {
    float x1 = av0[k] - p0[k] + m1[k];
    x1 = x1 > 0.f ? x1 : 0.2f * x1;
    float x2 = av1[k] - p1[k] + m2[k];
    x2 = x2 > 0.f ? x2 : 0.2f * x2;
    v[k] = hv[k] + 0.5f * (x1 + x2);
  }
  *(float4*)&h[(size_t)i * 128 + c] = make_float4(v[0], v[1], v[2], v[3]);
  *(float4*)&h[(size_t)i * 128 + c + 4] = make_float4(v[4], v[5], v[6], v[7]);
  uint4 pb = {pk2(v[0], v[1]), pk2(v[2], v[3]), pk2(v[4], v[5]), pk2(v[6], v[7])};
  *(uint4*)&hb[(size_t)i * 128 + c] = pb;
}

// ---------------------------------------------------------------------------
// Final projection: q = T @ Wr2 + br2   (T: [32768,128], Wr2: [128,3])
// ---------------------------------------------------------------------------
__global__ __launch_bounds__(128) void recon2_kernel(const float* __restrict__ T,
                                                     const float* __restrict__ Wr2,
                                                     const float* __restrict__ br2,
                                                     float* __restrict__ out) {
  __shared__ float tile[32][129];
  __shared__ float w2[384];
  const int tid = threadIdx.x;
  const int r0 = blockIdx.x * 32;
  w2[tid] = Wr2[tid];
  w2[tid + 128] = Wr2[tid + 128];
  w2[tid + 256] = Wr2[tid + 256];
  for (int s = 0; s < 32; ++s) tile[s][tid] = T[(size_t)(r0 + s) * 128 + tid];
  __syncthreads();
  if (tid < 96) {
    const int r = tid / 3, n = tid % 3;
    float acc = br2[n];
#pragma unroll
    for (int k = 0; k < 128; ++k) acc = fmaf(tile[r][k], w2[k * 3 + n], acc);
    out[(size_t)(r0 + r) * 3 + n] = acc;
  }
}

// ---------------------------------------------------------------------------
extern "C" void kernel_launch(void* const* d_in, const int* in_sizes, int n_in,
                              void* d_out, int out_size, void* d_ws, size_t ws_size,
                              hipStream_t stream) {
  const float* x = (const float*)d_in[0];
  const float* W0 = (const float*)d_in[1];
  const float* b0 = (const float*)d_in[2];
  const float* Wg = (const float*)d_in[3];
  const float* bg = (const float*)d_in[4];
  const float* Wu = (const float*)d_in[5];
  const float* bu = (const float*)d_in[6];
  const float* Wr1 = (const float*)d_in[7];
  const float* br1 = (const float*)d_in[8];
  const float* Wr2 = (const float*)d_in[9];
  const float* br2 = (const float*)d_in[10];
  float* out = (float*)d_out;

  char* w = (char*)d_ws;
  int* idx = (int*)(w + 0);              // 1,310,720
  float4* pos4 = (float4*)(w + 1310720); // 131,072
  float* h = (float*)(w + 1441792);      // 4 MB
  u16* hb = (u16*)(w + 5636096);         // 2 MB
  float* Apair = (float*)(w + 7733248);  // 8 MB   (Ub aliases)
  u16* Ppair = (u16*)(w + 16121856);     // 4 MB
  u16* Wgb = (u16*)(w + 20316160);       // 256 KB
  u16* Wub = (u16*)(w + 20578304);       // 256 KB
  u16* Wr1b = (u16*)(w + 20840448);      // 32 KB
  float* Abig = (float*)(w + 20873216);  // 16 MB  (T aliases)
  u16* Pbig = (u16*)(w + 37650432);      // 8 MB
  u16* Ub = (u16*)Apair;                 // Apair dead when Ub produced
  float* T = Abig;                       // Abig dead when T produced

  wcvt_kernel<<<1024, 128, 0, stream>>>(Wg, Wgb, 128, 256, 256 * 128);
  wcvt_kernel<<<1024, 128, 0, stream>>>(Wu, Wub, 512, 1024, 1024 * 128);
  wcvt_kernel<<<128, 128, 0, stream>>>(Wr1, Wr1b, 128, 128, 128 * 128);

  pos4_kernel<<<32, 256, 0, stream>>>(x, pos4);
  knn_kernel<<<N_PTS / QB, 256, 0, stream>>>(pos4, idx);

  // lift 3 -> 128
  lift_kernel<<<N_PTS, 128, 0, stream>>>(x, W0, b0, Abig, Pbig);
  gather_one_kernel<<<dim3(512, 1), 256, 0, stream>>>(Abig, Pbig, idx, 128, 1, h, hb);

  // 2 inception blocks, each = one pair-GEMM (N=512) + one fused gather
  for (int blk = 0; blk < 2; ++blk) {
    const int li = blk * 2;
    gemm_mfma_kernel<<<dim3(64, 8), 256, 0, stream>>>(
        hb, Wgb + (size_t)li * 256 * 128, bg + li * 128, 128, 8, 256, 256, 0.f, 0,
        Apair, Ppair);
    gather_pair_kernel<<<512, 256, 0, stream>>>(Apair, Ppair, idx, h, hb);
  }

  // NodeShuffle upsampler (r*C = 512), column-blocked gather
  gemm_mfma_kernel<<<dim3(64, 16), 256, 0, stream>>>(hb, Wub, bu, 512, 10, 512, 512,
                                                     0.f, 0, Abig, Pbig);
  gather_one_kernel<<<dim3(512, 4), 256, 0, stream>>>(Abig, Pbig, idx, 512, 1,
                                                      (float*)nullptr, Ub);

  // reconstructor MLP
  gemm_mfma_kernel<<<dim3(256, 2), 256, 0, stream>>>(Ub, Wr1b, br1, 128, 7, 128, 128,
                                                     0.01f, 1, T, (u16*)nullptr);
  recon2_kernel<<<1024, 128, 0, stream>>>(T, Wr2, br2, out);
}

// Round 5
// 166.295 us; speedup vs baseline: 3.6765x; 1.0712x over previous
//
#include <hip/hip_runtime.h>
#include <math.h>

#define N_PTS 8192
#define KFULL 40
#define KNB 20
#define QB 8
#define KBLK 512
#define NBUCK 1024
#define CAP 384

typedef unsigned short u16;
typedef unsigned int u32;
typedef unsigned long long u64;
typedef __attribute__((ext_vector_type(8))) short bf16x8;
typedef __attribute__((ext_vector_type(4))) float f32x4;

__device__ __forceinline__ u16 f2b(float v) {  // RNE float->bf16 bits
  u32 u = __float_as_uint(v);
  return (u16)((u + 0x7FFFu + ((u >> 16) & 1u)) >> 16);
}
__device__ __forceinline__ u32 pk2(float a, float b) {
  return (u32)f2b(a) | ((u32)f2b(b) << 16);
}
__device__ __forceinline__ u32 dmap(float d) {  // order-preserving float->u32
  u32 b = __float_as_uint(d);
  return b ^ ((u32)(((int)b) >> 31) | 0x80000000u);
}
__device__ __forceinline__ void maxu4(const uint4 v, float m[8]) {
  m[0] = fmaxf(m[0], __uint_as_float(v.x << 16));
  m[1] = fmaxf(m[1], __uint_as_float(v.x & 0xFFFF0000u));
  m[2] = fmaxf(m[2], __uint_as_float(v.y << 16));
  m[3] = fmaxf(m[3], __uint_as_float(v.y & 0xFFFF0000u));
  m[4] = fmaxf(m[4], __uint_as_float(v.z << 16));
  m[5] = fmaxf(m[5], __uint_as_float(v.z & 0xFFFF0000u));
  m[6] = fmaxf(m[6], __uint_as_float(v.w << 16));
  m[7] = fmaxf(m[7], __uint_as_float(v.w & 0xFFFF0000u));
}
__device__ __forceinline__ void unp4(const uint4 v, float p[8]) {
  p[0] = __uint_as_float(v.x << 16);
  p[1] = __uint_as_float(v.x & 0xFFFF0000u);
  p[2] = __uint_as_float(v.y << 16);
  p[3] = __uint_as_float(v.y & 0xFFFF0000u);
  p[4] = __uint_as_float(v.z << 16);
  p[5] = __uint_as_float(v.z & 0xFFFF0000u);
  p[6] = __uint_as_float(v.w << 16);
  p[7] = __uint_as_float(v.w & 0xFFFF0000u);
}

typedef const __attribute__((address_space(1))) unsigned int* gas_p;
typedef __attribute__((address_space(3))) unsigned int* las_p;
__device__ __forceinline__ void gll16(const void* g, void* l) {
  __builtin_amdgcn_global_load_lds((gas_p)g, (las_p)l, 16, 0, 0);
}

// ---------------------------------------------------------------------------
// scan over packed histograms: find bucket where cumulative (incl self) >= 41.
// Wave w handles hist[w] (queries 2w lo16, 2w+1 hi16); waves >= QB/2 idle.
// ---------------------------------------------------------------------------
__device__ __forceinline__ void scan_cut(const u32 (*hist)[NBUCK], int* s_cut,
                                         int t) {
  const int w = t >> 6, lane = t & 63;
  if (w < QB / 2) {
    const u32* H = hist[w];
    const int base = lane * (NBUCK / 64);
    u32 lsum = 0;
#pragma unroll
    for (int k = 0; k < NBUCK / 64; ++k) lsum += H[base + k];
    u32 inc = lsum;  // packed scan: halves < 2^15, no carry crossover
#pragma unroll
    for (int off = 1; off < 64; off <<= 1) {
      const u32 u = __shfl_up(inc, off);
      if (lane >= off) inc += u;
    }
    const u32 excl = inc - lsum;
    const u32 TGT = KFULL + 1;  // 41 incl. self
    const u32 exlo = excl & 0xFFFFu, inlo = inc & 0xFFFFu;
    if (exlo < TGT && inlo >= TGT) {
      u32 cum = exlo;
      for (int k = 0; k < NBUCK / 64; ++k) {
        cum += H[base + k] & 0xFFFFu;
        if (cum >= TGT) { s_cut[2 * w] = base + k; break; }
      }
    }
    const u32 exhi = excl >> 16, inhi = inc >> 16;
    if (exhi < TGT && inhi >= TGT) {
      u32 cum = exhi;
      for (int k = 0; k < NBUCK / 64; ++k) {
        cum += H[base + k] >> 16;
        if (cum >= TGT) { s_cut[2 * w + 1] = base + k; break; }
      }
    }
  }
}

// ---------------------------------------------------------------------------
// kNN v5: 8 queries / 512-thread block (full wave residency: 32 waves/CU).
// Phase 0: 512-pt subsample -> upper-bound bucket. Pass 1: filtered histogram.
// Pass 2: compact shell <= exact cutoff. Rank-sort (self = rank 0, dropped).
// ---------------------------------------------------------------------------
__global__ __launch_bounds__(KBLK) void knn_kernel(const float4* __restrict__ pos4,
                                                   int* __restrict__ idx_out) {
  __shared__ __align__(16) u32 hmem[CAP * QB * 2];  // 24576 B
  u32 (*hist)[NBUCK] = (u32(*)[NBUCK])hmem;          // 4 packed arrays
  u64 (*cand)[CAP] = (u64(*)[CAP])hmem;
  __shared__ float4 s_q[QB];
  __shared__ int s_cut[QB];
  __shared__ int s_cnt[QB];

  const int qb = blockIdx.x * QB, t = threadIdx.x;
  if (t < QB) {
    s_q[t] = pos4[qb + t];
    s_cnt[t] = 0;
  }
  for (int b = t; b < 4 * NBUCK; b += KBLK) hmem[b] = 0;
  __syncthreads();

  float qx[QB], qy[QB], qz[QB], qs[QB];
#pragma unroll
  for (int q = 0; q < QB; ++q) {
    const float4 v = s_q[q];
    qx[q] = -2.0f * v.x; qy[q] = -2.0f * v.y; qz[q] = -2.0f * v.z; qs[q] = v.w;
  }

  // ---- phase 0: subsample (stride 16, one point per thread) ----
  {
    const int j = t << 4;
    const float4 p = pos4[j];
#pragma unroll
    for (int q = 0; q < QB; ++q) {
      const float d = fmaf(qx[q], p.x, fmaf(qy[q], p.y, fmaf(qz[q], p.z, qs[q] + p.w)));
      const u32 bk = dmap(d) >> 22;
      atomicAdd(&hist[q >> 1][bk], 1u << ((q & 1) * 16));
    }
  }
  __syncthreads();
  scan_cut(hist, s_cut, t);
  __syncthreads();
  int bcut[QB];
#pragma unroll
  for (int q = 0; q < QB; ++q) bcut[q] = s_cut[q];
  for (int b = t; b < 4 * NBUCK; b += KBLK) hmem[b] = 0;
  __syncthreads();

  // ---- pass 1: filtered histogram ----
#pragma unroll 2
  for (int s = 0; s < 16; ++s) {
    const int j = t + (s << 9);
    const float4 p = pos4[j];
#pragma unroll
    for (int q = 0; q < QB; ++q) {
      const float d = fmaf(qx[q], p.x, fmaf(qy[q], p.y, fmaf(qz[q], p.z, qs[q] + p.w)));
      const u32 bk = dmap(d) >> 22;
      if ((int)bk <= bcut[q]) atomicAdd(&hist[q >> 1][bk], 1u << ((q & 1) * 16));
    }
  }
  __syncthreads();
  scan_cut(hist, s_cut, t);
  __syncthreads();
#pragma unroll
  for (int q = 0; q < QB; ++q) bcut[q] = s_cut[q];
  __syncthreads();  // hist reads done; hmem reused as cand below

  // ---- pass 2: compact shell ----
#pragma unroll 2
  for (int s = 0; s < 16; ++s) {
    const int j = t + (s << 9);
    const float4 p = pos4[j];
#pragma unroll
    for (int q = 0; q < QB; ++q) {
      const float d = fmaf(qx[q], p.x, fmaf(qy[q], p.y, fmaf(qz[q], p.z, qs[q] + p.w)));
      const u32 mp = dmap(d);
      if ((int)(mp >> 22) <= bcut[q]) {
        const int slot = atomicAdd(&s_cnt[q], 1);
        if (slot < CAP) cand[q][slot] = ((u64)mp << 13) | (u64)j;
      }
    }
  }
  __syncthreads();

  // ---- rank sort: wave w sorts query w ----
  {
    const int w = t >> 6, lane = t & 63;
    const int cnt = s_cnt[w] < CAP ? s_cnt[w] : CAP;
    for (int c0 = lane; c0 < cnt; c0 += 64) {
      const u64 my = cand[w][c0];
      int rank = 0;
      for (int c = 0; c < cnt; ++c) rank += (cand[w][c] < my) ? 1 : 0;
      if (rank >= 1 && rank <= KFULL)
        idx_out[(qb + w) * KFULL + (rank - 1)] = (int)(my & 0x1FFFull);
    }
  }
}

// ---------------------------------------------------------------------------
// Weight convert+transpose body: dst[r][k] = f2b(src[(part*128+k)*ncols+col])
// ---------------------------------------------------------------------------
__device__ __forceinline__ void wcvt_body(const float* __restrict__ src,
                                          u16* __restrict__ dst, int ncols,
                                          int rows_per_tensor, int elems_per_tensor,
                                          int rg, int k) {
  const int li = rg / rows_per_tensor;
  const int r = rg % rows_per_tensor;
  const float* s = src + (size_t)li * elems_per_tensor;
  u16* d = dst + (size_t)li * elems_per_tensor;
  const int part = r / ncols, col = r % ncols;
  d[(size_t)r * 128 + k] = f2b(s[(size_t)(part * 128 + k) * ncols + col]);
}

// ---------------------------------------------------------------------------
// Fused preamble: lift (blocks 0..8191) | Wg cvt | Wu cvt | Wr1 cvt | pos4.
// ---------------------------------------------------------------------------
__global__ __launch_bounds__(128) void prep_kernel(
    const float* __restrict__ x, const float* __restrict__ W0,
    const float* __restrict__ b0, const float* __restrict__ Wg,
    const float* __restrict__ Wu, const float* __restrict__ Wr1,
    float* __restrict__ Aout, u16* __restrict__ Pout, u16* __restrict__ Wgb,
    u16* __restrict__ Wub, u16* __restrict__ Wr1b, float4* __restrict__ pos4) {
  const int b = blockIdx.x, t = threadIdx.x;
  if (b < 8192) {  // lift: A = x@W0[0:3]+b0 (f32), P = x@W0[3:6] (bf16)
    const float px = x[b * 3 + 0], py = x[b * 3 + 1], pz = x[b * 3 + 2];
    const float a = b0[t] + px * W0[t] + py * W0[128 + t] + pz * W0[256 + t];
    const float p = px * W0[384 + t] + py * W0[512 + t] + pz * W0[640 + t];
    Aout[(size_t)b * 128 + t] = a;
    Pout[(size_t)b * 128 + t] = f2b(p);
  } else if (b < 9216) {
    wcvt_body(Wg, Wgb, 128, 256, 256 * 128, b - 8192, t);
  } else if (b < 10240) {
    wcvt_body(Wu, Wub, 512, 1024, 1024 * 128, b - 9216, t);
  } else if (b < 10368) {
    wcvt_body(Wr1, Wr1b, 128, 128, 128 * 128, b - 10240, t);
  } else {
    const int j = (b - 10368) * 128 + t;
    const float px = x[j * 3 + 0], py = x[j * 3 + 1], pz = x[j * 3 + 2];
    pos4[j] = make_float4(px, py, pz, px * px + py * py + pz * pz);
  }
}

// ---------------------------------------------------------------------------
// bf16 MFMA GEMM, K=128, BM=128, BN=64. Epilogue splits per-group cols into
// A (f32, +bias, opt act) and P (bf16).
// ---------------------------------------------------------------------------
__global__ __launch_bounds__(256) void gemm_mfma_kernel(
    const u16* __restrict__ Ain, const u16* __restrict__ Wt,
    const float* __restrict__ bias, int GA, int span_shift, int nAtot, int nPtot,
    float slope, int use_act, float* __restrict__ Aout, u16* __restrict__ Pout) {
  __shared__ __align__(16) u16 Al[128 * 128];
  __shared__ __align__(16) u16 Bl[64 * 128];
  const int bm = blockIdx.x * 128;
  const int bn = blockIdx.y * 64;
  const int tid = threadIdx.x;

#pragma unroll
  for (int it = 0; it < 8; ++it) {
    const int g = it * 256 + tid;
    const int row = g >> 4, cc = g & 15;
    const int sc = cc ^ (row & 7);
    gll16(Ain + (size_t)(bm + row) * 128 + sc * 8, &Al[g * 8]);
  }
#pragma unroll
  for (int it = 0; it < 4; ++it) {
    const int g = it * 256 + tid;
    const int row = g >> 4, cc = g & 15;
    const int sc = cc ^ (row & 7);
    gll16(Wt + (size_t)(bn + row) * 128 + sc * 8, &Bl[g * 8]);
  }
  __syncthreads();

  const int wv = tid >> 6, lane = tid & 63;
  const int wm = wv & 1, wn = wv >> 1;
  const int lr = lane & 15, lk = lane >> 4;

  bf16x8 a[4][4], b[2][4];
  f32x4 acc[4][2];
#pragma unroll
  for (int m = 0; m < 4; ++m)
#pragma unroll
    for (int n = 0; n < 2; ++n) acc[m][n] = (f32x4){0.f, 0.f, 0.f, 0.f};

#pragma unroll
  for (int m = 0; m < 4; ++m) {
    const int row = wm * 64 + m * 16 + lr;
#pragma unroll
    for (int ks = 0; ks < 4; ++ks) {
      const int c = ks * 4 + lk;
      a[m][ks] = *(const bf16x8*)&Al[row * 128 + (c ^ (row & 7)) * 8];
    }
  }
#pragma unroll
  for (int n = 0; n < 2; ++n) {
    const int col = wn * 32 + n * 16 + lr;
#pragma unroll
    for (int ks = 0; ks < 4; ++ks) {
      const int c = ks * 4 + lk;
      b[n][ks] = *(const bf16x8*)&Bl[col * 128 + (c ^ (col & 7)) * 8];
    }
  }

#pragma unroll
  for (int ks = 0; ks < 4; ++ks)
#pragma unroll
    for (int m = 0; m < 4; ++m)
#pragma unroll
      for (int n = 0; n < 2; ++n)
        acc[m][n] = __builtin_amdgcn_mfma_f32_16x16x32_bf16(a[m][ks], b[n][ks],
                                                            acc[m][n], 0, 0, 0);

  const int span = 1 << span_shift;
  const int GP = span - GA;
#pragma unroll
  for (int n = 0; n < 2; ++n) {
    const int col = bn + wn * 32 + n * 16 + lr;
    const int g = col >> span_shift;
    const int wi = col & (span - 1);
    const bool isA = wi < GA;
    const float bv = isA ? bias[g * GA + wi] : 0.f;
#pragma unroll
    for (int m = 0; m < 4; ++m) {
      const int row0 = bm + wm * 64 + m * 16 + lk * 4;
#pragma unroll
      for (int r = 0; r < 4; ++r) {
        float v = acc[m][n][r] + bv;
        if (isA) {
          if (use_act) v = v > 0.f ? v : v * slope;
          Aout[(size_t)(row0 + r) * nAtot + g * GA + wi] = v;
        } else {
          Pout[(size_t)(row0 + r) * nPtot + g * GP + (wi - GA)] = f2b(v);
        }
      }
    }
  }
}

// ---------------------------------------------------------------------------
// Single-branch gather-max: out = LR(A - P_self + max_j P[nbr_j], 0.2).
// 16 queries x 128 cols per block; P bf16 gathered as uint4 (8 cols/thread).
// ---------------------------------------------------------------------------
__global__ __launch_bounds__(256) void gather_one_kernel(
    const float* __restrict__ A, const u16* __restrict__ P,
    const int* __restrict__ idx, int C, int dil, float* __restrict__ outf,
    u16* __restrict__ outb) {
  const int t = threadIdx.x;
  const int i = blockIdx.x * 16 + (t >> 4);
  const int c = blockIdx.y * 128 + (t & 15) * 8;
  float m[8];
#pragma unroll
  for (int k = 0; k < 8; ++k) m[k] = -INFINITY;
  const int ib = i * KFULL;
#pragma unroll
  for (int j = 0; j < KNB; ++j) {
    const int n = idx[ib + j * dil] & (N_PTS - 1);
    maxu4(*(const uint4*)&P[(size_t)n * C + c], m);
  }
  float pv[8];
  unp4(*(const uint4*)&P[(size_t)i * C + c], pv);
  const float4 a0 = *(const float4*)&A[(size_t)i * C + c];
  const float4 a1 = *(const float4*)&A[(size_t)i * C + c + 4];
  const float av[8] = {a0.x, a0.y, a0.z, a0.w, a1.x, a1.y, a1.z, a1.w};
  float v[8];
#pragma unroll
  for (int k = 0; k < 8; ++k) {
    const float x = av[k] - pv[k] + m[k];
    v[k] = x > 0.f ? x : 0.2f * x;
  }
  if (outf) {
    *(float4*)&outf[(size_t)i * C + c] = make_float4(v[0], v[1], v[2], v[3]);
    *(float4*)&outf[(size_t)i * C + c + 4] = make_float4(v[4], v[5], v[6], v[7]);
  }
  if (outb) {
    uint4 pb = {pk2(v[0], v[1]), pk2(v[2], v[3]), pk2(v[4], v[5]), pk2(v[6], v[7])};
    *(uint4*)&outb[(size_t)i * C + c] = pb;
  }
}

// ---------------------------------------------------------------------------
// Fused inception pair: h += 0.5*(LR(A0-P0+max_dil1 P0) + LR(A1-P1+max_dil2 P1))
// ---------------------------------------------------------------------------
__global__ __launch_bounds__(256) void gather_pair_kernel(
    const float* __restrict__ Ap, const u16* __restrict__ Pp,
    const int* __restrict__ idx, float* __restrict__ h, u16* __restrict__ hb) {
  const int t = threadIdx.x;
  const int i = blockIdx.x * 16 + (t >> 4);
  const int c = (t & 15) * 8;
  float m1[8], m2[8];
#pragma unroll
  for (int k = 0; k < 8; ++k) { m1[k] = -INFINITY; m2[k] = -INFINITY; }
  const int ib = i * KFULL;
#pragma unroll
  for (int j = 0; j < KNB; ++j) {
    const int n1 = idx[ib + j] & (N_PTS - 1);
    maxu4(*(const uint4*)&Pp[(size_t)n1 * 256 + c], m1);
    const int n2 = idx[ib + 2 * j] & (N_PTS - 1);
    maxu4(*(const uint4*)&Pp[(size_t)n2 * 256 + 128 + c], m2);
  }
  float p0[8], p1[8];
  unp4(*(const uint4*)&Pp[(size_t)i * 256 + c], p0);
  unp4(*(const uint4*)&Pp[(size_t)i * 256 + 128 + c], p1);
  const float4 a00 = *(const float4*)&Ap[(size_t)i * 256 + c];
  const float4 a01 = *(const float4*)&Ap[(size_t)i * 256 + c + 4];
  const float4 a10 = *(const float4*)&Ap[(size_t)i * 256 + 128 + c];
  const float4 a11 = *(const float4*)&Ap[(size_t)i * 256 + 128 + c + 4];
  const float av0[8] = {a00.x, a00.y, a00.z, a00.w, a01.x, a01.y, a01.z, a01.w};
  const float av1[8] = {a10.x, a10.y, a10.z, a10.w, a11.x, a11.y, a11.z, a11.w};
  const float4 h0 = *(const float4*)&h[(size_t)i * 128 + c];
  const float4 h1 = *(const float4*)&h[(size_t)i * 128 + c + 4];
  const float hv[8] = {h0.x, h0.y, h0.z, h0.w, h1.x, h1.y, h1.z, h1.w};
  float v[8];
#pragma unroll
  for (int k = 0; k < 8; ++k) {
    float x1 = av0[k] - p0[k] + m1[k];
    x1 = x1 > 0.f ? x1 : 0.2f * x1;
    float x2 = av1[k] - p1[k] + m2[k];
    x2 = x2 > 0.f ? x2 : 0.2f * x2;
    v[k] = hv[k] + 0.5f * (x1 + x2);
  }
  *(float4*)&h[(size_t)i * 128 + c] = make_float4(v[0], v[1], v[2], v[3]);
  *(float4*)&h[(size_t)i * 128 + c + 4] = make_float4(v[4], v[5], v[6], v[7]);
  uint4 pb = {pk2(v[0], v[1]), pk2(v[2], v[3]), pk2(v[4], v[5]), pk2(v[6], v[7])};
  *(uint4*)&hb[(size_t)i * 128 + c] = pb;
}

// ---------------------------------------------------------------------------
// Final projection: q = T @ Wr2 + br2   (T: [32768,128], Wr2: [128,3])
// ---------------------------------------------------------------------------
__global__ __launch_bounds__(128) void recon2_kernel(const float* __restrict__ T,
                                                     const float* __restrict__ Wr2,
                                                     const float* __restrict__ br2,
                                                     float* __restrict__ out) {
  __shared__ float tile[32][129];
  __shared__ float w2[384];
  const int tid = threadIdx.x;
  const int r0 = blockIdx.x * 32;
  w2[tid] = Wr2[tid];
  w2[tid + 128] = Wr2[tid + 128];
  w2[tid + 256] = Wr2[tid + 256];
  for (int s = 0; s < 32; ++s) tile[s][tid] = T[(size_t)(r0 + s) * 128 + tid];
  __syncthreads();
  if (tid < 96) {
    const int r = tid / 3, n = tid % 3;
    float acc = br2[n];
#pragma unroll
    for (int k = 0; k < 128; ++k) acc = fmaf(tile[r][k], w2[k * 3 + n], acc);
    out[(size_t)(r0 + r) * 3 + n] = acc;
  }
}

// ---------------------------------------------------------------------------
extern "C" void kernel_launch(void* const* d_in, const int* in_sizes, int n_in,
                              void* d_out, int out_size, void* d_ws, size_t ws_size,
                              hipStream_t stream) {
  const float* x = (const float*)d_in[0];
  const float* W0 = (const float*)d_in[1];
  const float* b0 = (const float*)d_in[2];
  const float* Wg = (const float*)d_in[3];
  const float* bg = (const float*)d_in[4];
  const float* Wu = (const float*)d_in[5];
  const float* bu = (const float*)d_in[6];
  const float* Wr1 = (const float*)d_in[7];
  const float* br1 = (const float*)d_in[8];
  const float* Wr2 = (const float*)d_in[9];
  const float* br2 = (const float*)d_in[10];
  float* out = (float*)d_out;

  char* w = (char*)d_ws;
  int* idx = (int*)(w + 0);              // 1,310,720
  float4* pos4 = (float4*)(w + 1310720); // 131,072
  float* h = (float*)(w + 1441792);      // 4 MB
  u16* hb = (u16*)(w + 5636096);         // 2 MB
  float* Apair = (float*)(w + 7733248);  // 8 MB   (Ub aliases)
  u16* Ppair = (u16*)(w + 16121856);     // 4 MB
  u16* Wgb = (u16*)(w + 20316160);       // 256 KB
  u16* Wub = (u16*)(w + 20578304);       // 256 KB
  u16* Wr1b = (u16*)(w + 20840448);      // 32 KB
  float* Abig = (float*)(w + 20873216);  // 16 MB  (T aliases)
  u16* Pbig = (u16*)(w + 37650432);      // 8 MB
  u16* Ub = (u16*)Apair;                 // Apair dead when Ub produced
  float* T = Abig;                       // Abig dead when T produced

  // fused preamble: lift | Wg cvt | Wu cvt | Wr1 cvt | pos4
  prep_kernel<<<10432, 128, 0, stream>>>(x, W0, b0, Wg, Wu, Wr1, Abig, Pbig, Wgb,
                                         Wub, Wr1b, pos4);

  knn_kernel<<<N_PTS / QB, KBLK, 0, stream>>>(pos4, idx);

  gather_one_kernel<<<dim3(512, 1), 256, 0, stream>>>(Abig, Pbig, idx, 128, 1, h, hb);

  // 2 inception blocks, each = one pair-GEMM (N=512) + one fused gather
  for (int blk = 0; blk < 2; ++blk) {
    const int li = blk * 2;
    gemm_mfma_kernel<<<dim3(64, 8), 256, 0, stream>>>(
        hb, Wgb + (size_t)li * 256 * 128, bg + li * 128, 128, 8, 256, 256, 0.f, 0,
        Apair, Ppair);
    gather_pair_kernel<<<512, 256, 0, stream>>>(Apair, Ppair, idx, h, hb);
  }

  // NodeShuffle upsampler (r*C = 512), column-blocked gather
  gemm_mfma_kernel<<<dim3(64, 16), 256, 0, stream>>>(hb, Wub, bu, 512, 10, 512, 512,
                                                     0.f, 0, Abig, Pbig);
  gather_one_kernel<<<dim3(512, 4), 256, 0, stream>>>(Abig, Pbig, idx, 512, 1,
                                                      (float*)nullptr, Ub);

  // reconstructor MLP
  gemm_mfma_kernel<<<dim3(256, 2), 256, 0, stream>>>(Ub, Wr1b, br1, 128, 7, 128, 128,
                                                     0.01f, 1, T, (u16*)nullptr);
  recon2_kernel<<<1024, 128, 0, stream>>>(T, Wr2, br2, out);
}